// Round 1
// baseline (2830.644 us; speedup 1.0000x reference)
//
#include <hip/hip_runtime.h>
#include <cstddef>

#define N_H 8
#define N_C 32
#define N_HC 256
#define SLOPE 0.2f

// ---------- helpers ----------
__device__ __forceinline__ unsigned fenc(float f) {
    unsigned u = __float_as_uint(f);
    return (u & 0x80000000u) ? ~u : (u | 0x80000000u);
}
__device__ __forceinline__ float fdec(unsigned u) {
    return __uint_as_float((u & 0x80000000u) ? (u & 0x7FFFFFFFu) : ~u);
}

// ---------- preprocessing ----------
__global__ __launch_bounds__(256) void pre_x_kernel(const float* __restrict__ x,
                                                    float* __restrict__ xp, int Nn) {
    int i = blockIdx.x * blockDim.x + threadIdx.x;
    if (i >= Nn) return;
    float r[6];
#pragma unroll
    for (int j = 0; j < 6; ++j) r[j] = x[i * 6 + j];
    if (r[2] == 1.0f) r[1] = (r[1] - r[0]) * 0.01f;
#pragma unroll
    for (int j = 0; j < 6; ++j) xp[i * 6 + j] = r[j];
}

__global__ __launch_bounds__(256) void ea_colsum_kernel(const float* __restrict__ ea,
                                                        float* __restrict__ sums, int E) {
    float loc[11];
#pragma unroll
    for (int j = 0; j < 11; ++j) loc[j] = 0.f;
    for (int i = blockIdx.x * blockDim.x + threadIdx.x; i < E; i += gridDim.x * blockDim.x) {
        float r[11];
#pragma unroll
        for (int j = 0; j < 11; ++j) r[j] = ea[i * 11 + j];
        if (r[9] == 1.0f) r[1] = (r[1] - r[0]) * 0.01f;
#pragma unroll
        for (int j = 0; j < 11; ++j) loc[j] += r[j];
    }
    __shared__ float sbuf[256];
#pragma unroll
    for (int j = 0; j < 11; ++j) {
        sbuf[threadIdx.x] = loc[j];
        __syncthreads();
        for (int s = 128; s > 0; s >>= 1) {
            if (threadIdx.x < s) sbuf[threadIdx.x] += sbuf[threadIdx.x + s];
            __syncthreads();
        }
        if (threadIdx.x == 0) atomicAdd(&sums[j], sbuf[0]);
        __syncthreads();
    }
}

__global__ void mean_div_kernel(const float* __restrict__ sums, float* __restrict__ mean, int E) {
    int t = threadIdx.x;
    if (t < 11) mean[t] = sums[t] / (float)E;
}

// ---------- node transform: xl = X@Wl + bl, xr = X@Wr + br ----------
template <int K, int R>
__global__ __launch_bounds__(256) void node_mm_kernel(const float* __restrict__ X,
                                                      const float* __restrict__ Wl,
                                                      const float* __restrict__ bl,
                                                      const float* __restrict__ Wr,
                                                      const float* __restrict__ br,
                                                      float* __restrict__ xl,
                                                      float* __restrict__ xr, int Nn) {
    __shared__ float xs[R][K];
    int row0 = blockIdx.x * R;
    int tid = threadIdx.x;
    for (int i = tid; i < R * K; i += blockDim.x) {
        int r = i / K, k = i - r * K;
        int gr = row0 + r;
        xs[r][k] = (gr < Nn) ? X[(size_t)gr * K + k] : 0.f;
    }
    __syncthreads();
    int c = tid;  // 256 output columns
    float accl[R], accr[R];
#pragma unroll
    for (int r = 0; r < R; ++r) { accl[r] = bl[c]; accr[r] = br[c]; }
#pragma unroll 4
    for (int k = 0; k < K; ++k) {
        float wl = Wl[k * N_HC + c], wr = Wr[k * N_HC + c];
#pragma unroll
        for (int r = 0; r < R; ++r) {
            accl[r] = fmaf(xs[r][k], wl, accl[r]);
            accr[r] = fmaf(xs[r][k], wr, accr[r]);
        }
    }
#pragma unroll
    for (int r = 0; r < R; ++r) {
        int gr = row0 + r;
        if (gr < Nn) {
            xl[(size_t)gr * N_HC + c] = accl[r];
            xr[(size_t)gr * N_HC + c] = accr[r];
        }
    }
}

// ---------- edge pass 1: logits + segment max ----------
template <bool HAS_EDGE>
__global__ __launch_bounds__(256) void edge_logits_kernel(
    const int* __restrict__ ei, const float* __restrict__ ea, const float* __restrict__ mean_ea,
    const float* __restrict__ We, const float* __restrict__ att, const float* __restrict__ xl,
    const float* __restrict__ xr, float* __restrict__ logits, unsigned* __restrict__ mx, int E,
    int Etot) {
    int wid = threadIdx.x >> 6;
    int lane = threadIdx.x & 63;
    int e = blockIdx.x * (blockDim.x >> 6) + wid;
    if (e >= Etot) return;
    int src, tgt;
    if (e < E) { src = ei[e]; tgt = ei[E + e]; }
    else       { src = tgt = e - E; }
    int c4 = lane * 4;
    const float4 xlv = *(const float4*)(xl + (size_t)src * N_HC + c4);
    const float4 xrv = *(const float4*)(xr + (size_t)tgt * N_HC + c4);
    float m0 = xlv.x + xrv.x, m1 = xlv.y + xrv.y, m2 = xlv.z + xrv.z, m3 = xlv.w + xrv.w;
    if (HAS_EDGE) {
        float a = 0.f;
        if (e < E) {
            if (lane < 11) a = ea[(size_t)e * 11 + lane];
            float a0 = __shfl(a, 0);
            float a9 = __shfl(a, 9);
            if (lane == 1 && a9 == 1.0f) a = (a - a0) * 0.01f;
        } else {
            if (lane < 11) a = mean_ea[lane];
        }
#pragma unroll
        for (int j = 0; j < 11; ++j) {
            float aj = __shfl(a, j);
            const float4 wv = *(const float4*)(We + j * N_HC + c4);
            m0 = fmaf(aj, wv.x, m0);
            m1 = fmaf(aj, wv.y, m1);
            m2 = fmaf(aj, wv.z, m2);
            m3 = fmaf(aj, wv.w, m3);
        }
    }
    // leaky relu
    m0 = m0 > 0.f ? m0 : SLOPE * m0;
    m1 = m1 > 0.f ? m1 : SLOPE * m1;
    m2 = m2 > 0.f ? m2 : SLOPE * m2;
    m3 = m3 > 0.f ? m3 : SLOPE * m3;
    const float4 av = *(const float4*)(att + c4);
    float p = m0 * av.x + m1 * av.y + m2 * av.z + m3 * av.w;
    p += __shfl_xor(p, 1);
    p += __shfl_xor(p, 2);
    p += __shfl_xor(p, 4);
    if ((lane & 7) == 0) {
        int head = lane >> 3;
        logits[(size_t)e * N_H + head] = p;
        atomicMax(&mx[(size_t)tgt * N_H + head], fenc(p));
    }
}

// ---------- edge pass 2: ex, den, num ----------
__global__ __launch_bounds__(256) void edge_accum_kernel(const int* __restrict__ ei,
                                                         const float* __restrict__ logits,
                                                         const unsigned* __restrict__ mx,
                                                         const float* __restrict__ xl,
                                                         float* __restrict__ den,
                                                         float* __restrict__ num, int E, int Etot) {
    int wid = threadIdx.x >> 6;
    int lane = threadIdx.x & 63;
    int e = blockIdx.x * (blockDim.x >> 6) + wid;
    if (e >= Etot) return;
    int src, tgt;
    if (e < E) { src = ei[e]; tgt = ei[E + e]; }
    else       { src = tgt = e - E; }
    int head = lane >> 3;
    float logit = logits[(size_t)e * N_H + head];
    float mxv = fdec(mx[(size_t)tgt * N_H + head]);
    float ex = __expf(logit - mxv);
    if ((lane & 7) == 0) atomicAdd(&den[(size_t)tgt * N_H + head], ex);
    int c4 = lane * 4;
    const float4 xlv = *(const float4*)(xl + (size_t)src * N_HC + c4);
    float* dst = num + (size_t)tgt * N_HC + c4;
    atomicAdd(dst + 0, ex * xlv.x);
    atomicAdd(dst + 1, ex * xlv.y);
    atomicAdd(dst + 2, ex * xlv.z);
    atomicAdd(dst + 3, ex * xlv.w);
}

// ---------- node finalize: v = num/den + bias, optional ELU, in place ----------
template <bool ELU>
__global__ __launch_bounds__(256) void node_finalize_kernel(const float* __restrict__ den,
                                                            const float* __restrict__ bias,
                                                            float* __restrict__ inout, int Nn) {
    int i = blockIdx.x * blockDim.x + threadIdx.x;
    if (i >= Nn * N_HC) return;
    int node = i >> 8, ch = i & 255, head = ch >> 5;
    float v = inout[i] / den[node * N_H + head] + bias[ch];
    if (ELU) v = v > 0.f ? v : (__expf(v) - 1.f);
    inout[i] = v;
}

extern "C" void kernel_launch(void* const* d_in, const int* in_sizes, int n_in, void* d_out,
                              int out_size, void* d_ws, size_t ws_size, hipStream_t stream) {
    const float* x = (const float*)d_in[0];
    const int* ei = (const int*)d_in[1];
    const float* ea = (const float*)d_in[2];
    const float* Wl0 = (const float*)d_in[3];
    const float* bl0 = (const float*)d_in[4];
    const float* Wr0 = (const float*)d_in[5];
    const float* br0 = (const float*)d_in[6];
    const float* We0 = (const float*)d_in[7];
    const float* att0 = (const float*)d_in[8];
    const float* bias0 = (const float*)d_in[9];
    const float* Wl1 = (const float*)d_in[10];
    const float* bl1 = (const float*)d_in[11];
    const float* Wr1 = (const float*)d_in[12];
    const float* br1 = (const float*)d_in[13];
    const float* att1 = (const float*)d_in[14];
    const float* bias1 = (const float*)d_in[15];
    float* out = (float*)d_out;

    const int Nn = in_sizes[0] / 6;
    const int E = in_sizes[1] / 2;
    const int Etot = E + Nn;

    float* ws = (float*)d_ws;
    size_t o = 0;
    float* xp = ws + o;      o += (size_t)Nn * 6;
    float* xl = ws + o;      o += (size_t)Nn * N_HC;
    float* xr = ws + o;      o += (size_t)Nn * N_HC;
    float* num = ws + o;     o += (size_t)Nn * N_HC;   // also holds h after finalize
    float* logits = ws + o;  o += (size_t)Etot * N_H;
    unsigned* mx = (unsigned*)(ws + o); o += (size_t)Nn * N_H;
    float* den = ws + o;     o += (size_t)Nn * N_H;
    float* easum = ws + o;   o += 16;
    float* mean = ws + o;    o += 16;

    // zero-init (deterministic per call)
    hipMemsetAsync(easum, 0, 32 * sizeof(float), stream);
    hipMemsetAsync(mx, 0, (size_t)Nn * N_H * sizeof(float) * 2, stream);  // mx + den
    hipMemsetAsync(num, 0, (size_t)Nn * N_HC * sizeof(float), stream);
    hipMemsetAsync(d_out, 0, (size_t)out_size * sizeof(float), stream);

    // preprocessing
    pre_x_kernel<<<(Nn + 255) / 256, 256, 0, stream>>>(x, xp, Nn);
    ea_colsum_kernel<<<256, 256, 0, stream>>>(ea, easum, E);
    mean_div_kernel<<<1, 32, 0, stream>>>(easum, mean, E);

    // layer 0 node transforms (K=6)
    node_mm_kernel<6, 8><<<(Nn + 7) / 8, 256, 0, stream>>>(xp, Wl0, bl0, Wr0, br0, xl, xr, Nn);

    const int eblocks = (Etot + 3) / 4;
    edge_logits_kernel<true><<<eblocks, 256, 0, stream>>>(ei, ea, mean, We0, att0, xl, xr, logits,
                                                          mx, E, Etot);
    edge_accum_kernel<<<eblocks, 256, 0, stream>>>(ei, logits, mx, xl, den, num, E, Etot);
    node_finalize_kernel<true><<<(Nn * N_HC + 255) / 256, 256, 0, stream>>>(den, bias0, num, Nn);

    // layer 1
    hipMemsetAsync(mx, 0, (size_t)Nn * N_H * sizeof(float) * 2, stream);  // re-zero mx + den
    node_mm_kernel<256, 8><<<(Nn + 7) / 8, 256, 0, stream>>>(num, Wl1, bl1, Wr1, br1, xl, xr, Nn);
    edge_logits_kernel<false><<<eblocks, 256, 0, stream>>>(ei, nullptr, nullptr, nullptr, att1, xl,
                                                           xr, logits, mx, E, Etot);
    edge_accum_kernel<<<eblocks, 256, 0, stream>>>(ei, logits, mx, xl, den, out, E, Etot);
    node_finalize_kernel<false><<<(Nn * N_HC + 255) / 256, 256, 0, stream>>>(den, bias1, out, Nn);
}

// Round 2
// 469.465 us; speedup vs baseline: 6.0295x; 6.0295x over previous
//
#include <hip/hip_runtime.h>
#include <cstddef>

#define N_H 8
#define N_C 32
#define N_HC 256
#define SLOPE 0.2f

// ---------- preprocessing ----------
__global__ __launch_bounds__(256) void pre_x_kernel(const float* __restrict__ x,
                                                    float* __restrict__ xp, int Nn) {
    int i = blockIdx.x * blockDim.x + threadIdx.x;
    if (i >= Nn) return;
    float r[6];
#pragma unroll
    for (int j = 0; j < 6; ++j) r[j] = x[i * 6 + j];
    if (r[2] == 1.0f) r[1] = (r[1] - r[0]) * 0.01f;
#pragma unroll
    for (int j = 0; j < 6; ++j) xp[i * 6 + j] = r[j];
}

__global__ __launch_bounds__(256) void ea_colsum_kernel(const float* __restrict__ ea,
                                                        float* __restrict__ sums, int E) {
    float loc[11];
#pragma unroll
    for (int j = 0; j < 11; ++j) loc[j] = 0.f;
    for (int i = blockIdx.x * blockDim.x + threadIdx.x; i < E; i += gridDim.x * blockDim.x) {
        float r[11];
#pragma unroll
        for (int j = 0; j < 11; ++j) r[j] = ea[i * 11 + j];
        if (r[9] == 1.0f) r[1] = (r[1] - r[0]) * 0.01f;
#pragma unroll
        for (int j = 0; j < 11; ++j) loc[j] += r[j];
    }
    __shared__ float sbuf[256];
#pragma unroll
    for (int j = 0; j < 11; ++j) {
        sbuf[threadIdx.x] = loc[j];
        __syncthreads();
        for (int s = 128; s > 0; s >>= 1) {
            if (threadIdx.x < s) sbuf[threadIdx.x] += sbuf[threadIdx.x + s];
            __syncthreads();
        }
        if (threadIdx.x == 0) atomicAdd(&sums[j], sbuf[0]);
        __syncthreads();
    }
}

__global__ void mean_div_kernel(const float* __restrict__ sums, float* __restrict__ mean, int E) {
    int t = threadIdx.x;
    if (t < 11) mean[t] = sums[t] / (float)E;
}

// ---------- CSR build ----------
__global__ __launch_bounds__(256) void deg_hist_kernel(const int* __restrict__ ei,
                                                       int* __restrict__ deg, int E, int Etot) {
    int e = blockIdx.x * blockDim.x + threadIdx.x;
    if (e >= Etot) return;
    int t = (e < E) ? ei[E + e] : e - E;
    atomicAdd(&deg[t], 1);
}

__global__ __launch_bounds__(1024) void scan_kernel(const int* __restrict__ deg,
                                                    int* __restrict__ offs,
                                                    int* __restrict__ cursor, int Nn) {
    const int T = 1024;
    int tid = threadIdx.x;
    int chunk = (Nn + T - 1) / T;
    int b = tid * chunk;
    int s = 0;
    for (int k = 0; k < chunk; ++k) {
        int i = b + k;
        if (i < Nn) s += deg[i];
    }
    __shared__ int sm[T];
    sm[tid] = s;
    __syncthreads();
    for (int d = 1; d < T; d <<= 1) {
        int v = (tid >= d) ? sm[tid - d] : 0;
        __syncthreads();
        sm[tid] += v;
        __syncthreads();
    }
    int pref = (tid > 0) ? sm[tid - 1] : 0;
    for (int k = 0; k < chunk; ++k) {
        int i = b + k;
        if (i < Nn) {
            offs[i] = pref;
            cursor[i] = pref;
            pref += deg[i];
        }
    }
    if (tid == T - 1) offs[Nn] = sm[T - 1];
}

__global__ __launch_bounds__(256) void scatter_kernel(const int* __restrict__ ei,
                                                      int* __restrict__ cursor,
                                                      int* __restrict__ esrc,
                                                      int* __restrict__ eidx, int E, int Etot) {
    int e = blockIdx.x * blockDim.x + threadIdx.x;
    if (e >= Etot) return;
    int s, t;
    if (e < E) { s = ei[e]; t = ei[E + e]; }
    else       { s = t = e - E; }
    int pos = atomicAdd(&cursor[t], 1);
    esrc[pos] = s;
    eidx[pos] = e;
}

// ---------- node transform: xl = X@Wl + bl, xr = X@Wr + br ----------
template <int K, int R>
__global__ __launch_bounds__(256) void node_mm_kernel(const float* __restrict__ X,
                                                      const float* __restrict__ Wl,
                                                      const float* __restrict__ bl,
                                                      const float* __restrict__ Wr,
                                                      const float* __restrict__ br,
                                                      float* __restrict__ xl,
                                                      float* __restrict__ xr, int Nn) {
    __shared__ float xs[R][K];
    int row0 = blockIdx.x * R;
    int tid = threadIdx.x;
    for (int i = tid; i < R * K; i += blockDim.x) {
        int r = i / K, k = i - r * K;
        int gr = row0 + r;
        xs[r][k] = (gr < Nn) ? X[(size_t)gr * K + k] : 0.f;
    }
    __syncthreads();
    int c = tid;
    float accl[R], accr[R];
#pragma unroll
    for (int r = 0; r < R; ++r) { accl[r] = bl[c]; accr[r] = br[c]; }
#pragma unroll 4
    for (int k = 0; k < K; ++k) {
        float wl = Wl[k * N_HC + c], wr = Wr[k * N_HC + c];
#pragma unroll
        for (int r = 0; r < R; ++r) {
            accl[r] = fmaf(xs[r][k], wl, accl[r]);
            accr[r] = fmaf(xs[r][k], wr, accr[r]);
        }
    }
#pragma unroll
    for (int r = 0; r < R; ++r) {
        int gr = row0 + r;
        if (gr < Nn) {
            xl[(size_t)gr * N_HC + c] = accl[r];
            xr[(size_t)gr * N_HC + c] = accr[r];
        }
    }
}

// ---------- online softmax update ----------
__device__ __forceinline__ void online_update(float logit, const float4& xlv, float& m,
                                              float& den, float4& acc) {
    float mn = fmaxf(m, logit);
    float s = __expf(m - mn);
    float w = __expf(logit - mn);
    den = den * s + w;
    acc.x = fmaf(w, xlv.x, acc.x * s);
    acc.y = fmaf(w, xlv.y, acc.y * s);
    acc.z = fmaf(w, xlv.z, acc.z * s);
    acc.w = fmaf(w, xlv.w, acc.w * s);
    m = mn;
}

template <bool L0>
__device__ __forceinline__ float edge_logit(const float4& xlv, const float4& xrv,
                                            const float4* Wreg, float a, const float4& av) {
    float m0 = xlv.x + xrv.x, m1 = xlv.y + xrv.y, m2 = xlv.z + xrv.z, m3 = xlv.w + xrv.w;
    if (L0) {
#pragma unroll
        for (int j = 0; j < 11; ++j) {
            float aj = __shfl(a, j);
            m0 = fmaf(aj, Wreg[j].x, m0);
            m1 = fmaf(aj, Wreg[j].y, m1);
            m2 = fmaf(aj, Wreg[j].z, m2);
            m3 = fmaf(aj, Wreg[j].w, m3);
        }
    }
    m0 = m0 > 0.f ? m0 : SLOPE * m0;
    m1 = m1 > 0.f ? m1 : SLOPE * m1;
    m2 = m2 > 0.f ? m2 : SLOPE * m2;
    m3 = m3 > 0.f ? m3 : SLOPE * m3;
    float p = m0 * av.x + m1 * av.y + m2 * av.z + m3 * av.w;
    p += __shfl_xor(p, 1);
    p += __shfl_xor(p, 2);
    p += __shfl_xor(p, 4);
    return p;
}

// ---------- fused per-node gather: logits + online softmax + accumulate ----------
template <bool L0>
__global__ __launch_bounds__(256) void node_gather_kernel(
    const int* __restrict__ offs, const int* __restrict__ esrc, const int* __restrict__ eidx,
    const float* __restrict__ ea, const float* __restrict__ mean_ea,
    const float* __restrict__ We, const float* __restrict__ att, const float* __restrict__ xl,
    const float* __restrict__ xr, const float* __restrict__ bias, float* __restrict__ out,
    int Nn, int E) {
    int wid = threadIdx.x >> 6;
    int lane = threadIdx.x & 63;
    int node = blockIdx.x * 4 + wid;
    if (node >= Nn) return;
    int c4 = lane * 4;

    float4 Wreg[11];
    if (L0) {
#pragma unroll
        for (int j = 0; j < 11; ++j) Wreg[j] = *(const float4*)(We + j * N_HC + c4);
    }
    const float4 xrv = *(const float4*)(xr + (size_t)node * N_HC + c4);
    const float4 av = *(const float4*)(att + c4);

    int beg = offs[node], end = offs[node + 1];

    float mA = -INFINITY, dA = 0.f;
    float mB = -INFINITY, dB = 0.f;
    float4 aA = {0.f, 0.f, 0.f, 0.f}, aB = {0.f, 0.f, 0.f, 0.f};

    int p = beg;
    for (; p + 1 < end; p += 2) {
        int s0 = esrc[p], s1 = esrc[p + 1];
        const float4 x0 = *(const float4*)(xl + (size_t)s0 * N_HC + c4);
        const float4 x1 = *(const float4*)(xl + (size_t)s1 * N_HC + c4);
        float a0 = 0.f, a1 = 0.f;
        if (L0) {
            int e0 = eidx[p], e1 = eidx[p + 1];
            if (lane < 11) {
                a0 = (e0 < E) ? ea[(size_t)e0 * 11 + lane] : mean_ea[lane];
                a1 = (e1 < E) ? ea[(size_t)e1 * 11 + lane] : mean_ea[lane];
            }
            float q00 = __shfl(a0, 0), q09 = __shfl(a0, 9);
            float q10 = __shfl(a1, 0), q19 = __shfl(a1, 9);
            if (e0 < E && lane == 1 && q09 == 1.0f) a0 = (a0 - q00) * 0.01f;
            if (e1 < E && lane == 1 && q19 == 1.0f) a1 = (a1 - q10) * 0.01f;
        }
        float p0 = edge_logit<L0>(x0, xrv, Wreg, a0, av);
        float p1 = edge_logit<L0>(x1, xrv, Wreg, a1, av);
        online_update(p0, x0, mA, dA, aA);
        online_update(p1, x1, mB, dB, aB);
    }
    if (p < end) {
        int s0 = esrc[p];
        const float4 x0 = *(const float4*)(xl + (size_t)s0 * N_HC + c4);
        float a0 = 0.f;
        if (L0) {
            int e0 = eidx[p];
            if (lane < 11) a0 = (e0 < E) ? ea[(size_t)e0 * 11 + lane] : mean_ea[lane];
            float q00 = __shfl(a0, 0), q09 = __shfl(a0, 9);
            if (e0 < E && lane == 1 && q09 == 1.0f) a0 = (a0 - q00) * 0.01f;
        }
        float p0 = edge_logit<L0>(x0, xrv, Wreg, a0, av);
        online_update(p0, x0, mA, dA, aA);
    }

    // merge B into A
    float mm = fmaxf(mA, mB);
    float sA = __expf(mA - mm), sB = __expf(mB - mm);
    float den = dA * sA + dB * sB;
    float4 acc;
    acc.x = aA.x * sA + aB.x * sB;
    acc.y = aA.y * sA + aB.y * sB;
    acc.z = aA.z * sA + aB.z * sB;
    acc.w = aA.w * sA + aB.w * sB;

    const float4 bv = *(const float4*)(bias + c4);
    float4 r;
    r.x = acc.x / den + bv.x;
    r.y = acc.y / den + bv.y;
    r.z = acc.z / den + bv.z;
    r.w = acc.w / den + bv.w;
    if (L0) {
        r.x = r.x > 0.f ? r.x : (__expf(r.x) - 1.f);
        r.y = r.y > 0.f ? r.y : (__expf(r.y) - 1.f);
        r.z = r.z > 0.f ? r.z : (__expf(r.z) - 1.f);
        r.w = r.w > 0.f ? r.w : (__expf(r.w) - 1.f);
    }
    *(float4*)(out + (size_t)node * N_HC + c4) = r;
}

extern "C" void kernel_launch(void* const* d_in, const int* in_sizes, int n_in, void* d_out,
                              int out_size, void* d_ws, size_t ws_size, hipStream_t stream) {
    const float* x = (const float*)d_in[0];
    const int* ei = (const int*)d_in[1];
    const float* ea = (const float*)d_in[2];
    const float* Wl0 = (const float*)d_in[3];
    const float* bl0 = (const float*)d_in[4];
    const float* Wr0 = (const float*)d_in[5];
    const float* br0 = (const float*)d_in[6];
    const float* We0 = (const float*)d_in[7];
    const float* att0 = (const float*)d_in[8];
    const float* bias0 = (const float*)d_in[9];
    const float* Wl1 = (const float*)d_in[10];
    const float* bl1 = (const float*)d_in[11];
    const float* Wr1 = (const float*)d_in[12];
    const float* br1 = (const float*)d_in[13];
    const float* att1 = (const float*)d_in[14];
    const float* bias1 = (const float*)d_in[15];
    float* out = (float*)d_out;

    const int Nn = in_sizes[0] / 6;
    const int E = in_sizes[1] / 2;
    const int Etot = E + Nn;

    auto align16 = [](size_t v) { return (v + 15) & ~(size_t)15; };
    float* ws = (float*)d_ws;
    size_t o = 0;
    float* xp = ws + o;    o = align16(o + (size_t)Nn * 6);
    float* xl = ws + o;    o = align16(o + (size_t)Nn * N_HC);
    float* xr = ws + o;    o = align16(o + (size_t)Nn * N_HC);
    float* h = ws + o;     o = align16(o + (size_t)Nn * N_HC);
    float* easum = ws + o; o = align16(o + 16);
    float* mean = ws + o;  o = align16(o + 16);
    int* deg = (int*)(ws + o);    o = align16(o + (size_t)Nn);
    int* offs = (int*)(ws + o);   o = align16(o + (size_t)Nn + 1);
    int* cursor = (int*)(ws + o); o = align16(o + (size_t)Nn);
    int* esrc = (int*)(ws + o);   o = align16(o + (size_t)Etot);
    int* eidx = (int*)(ws + o);   o = align16(o + (size_t)Etot);

    // zero-init only what accumulates
    hipMemsetAsync(easum, 0, 16 * sizeof(float), stream);
    hipMemsetAsync(deg, 0, (size_t)Nn * sizeof(int), stream);

    // preprocessing
    pre_x_kernel<<<(Nn + 255) / 256, 256, 0, stream>>>(x, xp, Nn);
    ea_colsum_kernel<<<256, 256, 0, stream>>>(ea, easum, E);
    mean_div_kernel<<<1, 32, 0, stream>>>(easum, mean, E);

    // CSR build (shared across both layers)
    deg_hist_kernel<<<(Etot + 255) / 256, 256, 0, stream>>>(ei, deg, E, Etot);
    scan_kernel<<<1, 1024, 0, stream>>>(deg, offs, cursor, Nn);
    scatter_kernel<<<(Etot + 255) / 256, 256, 0, stream>>>(ei, cursor, esrc, eidx, E, Etot);

    const int gblocks = (Nn + 3) / 4;

    // layer 0
    node_mm_kernel<6, 8><<<(Nn + 7) / 8, 256, 0, stream>>>(xp, Wl0, bl0, Wr0, br0, xl, xr, Nn);
    node_gather_kernel<true><<<gblocks, 256, 0, stream>>>(offs, esrc, eidx, ea, mean, We0, att0,
                                                          xl, xr, bias0, h, Nn, E);

    // layer 1
    node_mm_kernel<256, 8><<<(Nn + 7) / 8, 256, 0, stream>>>(h, Wl1, bl1, Wr1, br1, xl, xr, Nn);
    node_gather_kernel<false><<<gblocks, 256, 0, stream>>>(offs, esrc, eidx, nullptr, nullptr,
                                                           nullptr, att1, xl, xr, bias1, out, Nn,
                                                           E);
}

// Round 3
// 385.687 us; speedup vs baseline: 7.3392x; 1.2172x over previous
//
#include <hip/hip_runtime.h>
#include <cstddef>

#define N_H 8
#define N_C 32
#define N_HC 256
#define SLOPE 0.2f

// ---------- preprocessing ----------
__global__ __launch_bounds__(256) void pre_x_kernel(const float* __restrict__ x,
                                                    float* __restrict__ xp, int Nn) {
    int i = blockIdx.x * blockDim.x + threadIdx.x;
    if (i >= Nn) return;
    float r[6];
#pragma unroll
    for (int j = 0; j < 6; ++j) r[j] = x[i * 6 + j];
    if (r[2] == 1.0f) r[1] = (r[1] - r[0]) * 0.01f;
#pragma unroll
    for (int j = 0; j < 6; ++j) xp[i * 6 + j] = r[j];
}

__global__ __launch_bounds__(256) void ea_colsum_kernel(const float* __restrict__ ea,
                                                        float* __restrict__ sums, int E) {
    float loc[11];
#pragma unroll
    for (int j = 0; j < 11; ++j) loc[j] = 0.f;
    for (int i = blockIdx.x * blockDim.x + threadIdx.x; i < E; i += gridDim.x * blockDim.x) {
        float r[11];
#pragma unroll
        for (int j = 0; j < 11; ++j) r[j] = ea[i * 11 + j];
        if (r[9] == 1.0f) r[1] = (r[1] - r[0]) * 0.01f;
#pragma unroll
        for (int j = 0; j < 11; ++j) loc[j] += r[j];
    }
    __shared__ float sbuf[256];
#pragma unroll
    for (int j = 0; j < 11; ++j) {
        sbuf[threadIdx.x] = loc[j];
        __syncthreads();
        for (int s = 128; s > 0; s >>= 1) {
            if (threadIdx.x < s) sbuf[threadIdx.x] += sbuf[threadIdx.x + s];
            __syncthreads();
        }
        if (threadIdx.x == 0) atomicAdd(&sums[j], sbuf[0]);
        __syncthreads();
    }
}

__global__ void mean_div_kernel(const float* __restrict__ sums, float* __restrict__ mean, int E) {
    int t = threadIdx.x;
    if (t < 11) mean[t] = sums[t] / (float)E;
}

// ---------- CSR build ----------
__global__ __launch_bounds__(256) void deg_hist_kernel(const int* __restrict__ ei,
                                                       int* __restrict__ deg, int E, int Etot) {
    int e = blockIdx.x * blockDim.x + threadIdx.x;
    if (e >= Etot) return;
    int t = (e < E) ? ei[E + e] : e - E;
    atomicAdd(&deg[t], 1);
}

__global__ __launch_bounds__(1024) void scan_kernel(const int* __restrict__ deg,
                                                    int* __restrict__ offs,
                                                    int* __restrict__ cursor, int Nn) {
    const int T = 1024;
    int tid = threadIdx.x;
    int chunk = (Nn + T - 1) / T;
    int b = tid * chunk;
    int s = 0;
    for (int k = 0; k < chunk; ++k) {
        int i = b + k;
        if (i < Nn) s += deg[i];
    }
    __shared__ int sm[T];
    sm[tid] = s;
    __syncthreads();
    for (int d = 1; d < T; d <<= 1) {
        int v = (tid >= d) ? sm[tid - d] : 0;
        __syncthreads();
        sm[tid] += v;
        __syncthreads();
    }
    int pref = (tid > 0) ? sm[tid - 1] : 0;
    for (int k = 0; k < chunk; ++k) {
        int i = b + k;
        if (i < Nn) {
            offs[i] = pref;
            cursor[i] = pref;
            pref += deg[i];
        }
    }
    if (tid == T - 1) offs[Nn] = sm[T - 1];
}

__global__ __launch_bounds__(256) void scatter_kernel(const int* __restrict__ ei,
                                                      int* __restrict__ cursor,
                                                      int* __restrict__ esrc,
                                                      int* __restrict__ eidx, int E, int Etot) {
    int e = blockIdx.x * blockDim.x + threadIdx.x;
    if (e >= Etot) return;
    int s, t;
    if (e < E) { s = ei[e]; t = ei[E + e]; }
    else       { s = t = e - E; }
    int pos = atomicAdd(&cursor[t], 1);
    esrc[pos] = s;
    eidx[pos] = e;
}

// ---------- layer-0 node transform (K=6) ----------
template <int K, int R>
__global__ __launch_bounds__(256) void node_mm_kernel(const float* __restrict__ X,
                                                      const float* __restrict__ Wl,
                                                      const float* __restrict__ bl,
                                                      const float* __restrict__ Wr,
                                                      const float* __restrict__ br,
                                                      float* __restrict__ xl,
                                                      float* __restrict__ xr, int Nn) {
    __shared__ float xs[R][K];
    int row0 = blockIdx.x * R;
    int tid = threadIdx.x;
    for (int i = tid; i < R * K; i += blockDim.x) {
        int r = i / K, k = i - r * K;
        int gr = row0 + r;
        xs[r][k] = (gr < Nn) ? X[(size_t)gr * K + k] : 0.f;
    }
    __syncthreads();
    int c = tid;
    float accl[R], accr[R];
#pragma unroll
    for (int r = 0; r < R; ++r) { accl[r] = bl[c]; accr[r] = br[c]; }
#pragma unroll
    for (int k = 0; k < K; ++k) {
        float wl = Wl[k * N_HC + c], wr = Wr[k * N_HC + c];
#pragma unroll
        for (int r = 0; r < R; ++r) {
            accl[r] = fmaf(xs[r][k], wl, accl[r]);
            accr[r] = fmaf(xs[r][k], wr, accr[r]);
        }
    }
#pragma unroll
    for (int r = 0; r < R; ++r) {
        int gr = row0 + r;
        if (gr < Nn) {
            xl[(size_t)gr * N_HC + c] = accl[r];
            xr[(size_t)gr * N_HC + c] = accr[r];
        }
    }
}

// ---------- layer-1 node transform: tiled f32 GEMM (K=256) ----------
// C[M,512] = X[M,256] @ [Wl | Wr]; BM=128, BN=128, BK=32; 8x8 per thread.
__global__ __launch_bounds__(256) void gemm256_kernel(const float* __restrict__ X,
                                                      const float* __restrict__ Wl,
                                                      const float* __restrict__ bl,
                                                      const float* __restrict__ Wr,
                                                      const float* __restrict__ br,
                                                      float* __restrict__ xl,
                                                      float* __restrict__ xr, int Nn) {
    __shared__ float As[32][128];  // transposed: As[k][row]
    __shared__ float Bs[32][128];  // Bs[k][col]

    const int by = blockIdx.y;
    const float* __restrict__ W = (by < 2) ? Wl : Wr;
    const float* __restrict__ bias = (by < 2) ? bl : br;
    float* __restrict__ dst = (by < 2) ? xl : xr;
    const int cb = (by & 1) * 128;
    const int row0 = blockIdx.x * 128;
    const int tid = threadIdx.x;
    const int tx = tid & 15, ty = tid >> 4;
    const int tx4 = tx * 4, ty4 = ty * 4;

    // staging coords
    const int arow = tid & 127;        // A: one row, 16 k's
    const int akh = (tid >> 7) * 16;   // 0 or 16
    const int bk0 = tid >> 5;          // B: rows bk0, bk0+8, bk0+16, bk0+24
    const int bc4 = (tid & 31) * 4;    // 32 lanes cover 128 cols

    float acc[8][8];
#pragma unroll
    for (int i = 0; i < 8; ++i)
#pragma unroll
        for (int j = 0; j < 8; ++j) acc[i][j] = 0.f;

    const int garow = row0 + arow;
    const bool aval = garow < Nn;
    const float* __restrict__ asrc = X + (size_t)garow * 256 + akh;

    for (int s = 0; s < 256; s += 32) {
        // stage A (transposed)
        float4 av[4];
#pragma unroll
        for (int q = 0; q < 4; ++q)
            av[q] = aval ? *(const float4*)(asrc + s + q * 4)
                         : float4{0.f, 0.f, 0.f, 0.f};
#pragma unroll
        for (int q = 0; q < 4; ++q) {
            As[akh + q * 4 + 0][arow] = av[q].x;
            As[akh + q * 4 + 1][arow] = av[q].y;
            As[akh + q * 4 + 2][arow] = av[q].z;
            As[akh + q * 4 + 3][arow] = av[q].w;
        }
        // stage B
#pragma unroll
        for (int q = 0; q < 4; ++q) {
            int kr = bk0 + q * 8;
            *(float4*)&Bs[kr][bc4] = *(const float4*)(W + (size_t)(s + kr) * 256 + cb + bc4);
        }
        __syncthreads();
#pragma unroll 8
        for (int k = 0; k < 32; ++k) {
            const float4 a0 = *(const float4*)&As[k][ty4];
            const float4 a1 = *(const float4*)&As[k][64 + ty4];
            const float4 b0 = *(const float4*)&Bs[k][tx4];
            const float4 b1 = *(const float4*)&Bs[k][64 + tx4];
            const float ar[8] = {a0.x, a0.y, a0.z, a0.w, a1.x, a1.y, a1.z, a1.w};
            const float brr[8] = {b0.x, b0.y, b0.z, b0.w, b1.x, b1.y, b1.z, b1.w};
#pragma unroll
            for (int i = 0; i < 8; ++i)
#pragma unroll
                for (int j = 0; j < 8; ++j) acc[i][j] = fmaf(ar[i], brr[j], acc[i][j]);
        }
        __syncthreads();
    }

    const float4 bv0 = *(const float4*)(bias + cb + tx4);
    const float4 bv1 = *(const float4*)(bias + cb + 64 + tx4);
#pragma unroll
    for (int i = 0; i < 8; ++i) {
        int r = row0 + ((i < 4) ? (ty4 + i) : (64 + ty4 + i - 4));
        if (r < Nn) {
            float4 v0 = {acc[i][0] + bv0.x, acc[i][1] + bv0.y, acc[i][2] + bv0.z,
                         acc[i][3] + bv0.w};
            float4 v1 = {acc[i][4] + bv1.x, acc[i][5] + bv1.y, acc[i][6] + bv1.z,
                         acc[i][7] + bv1.w};
            *(float4*)(dst + (size_t)r * N_HC + cb + tx4) = v0;
            *(float4*)(dst + (size_t)r * N_HC + cb + 64 + tx4) = v1;
        }
    }
}

// ---------- online softmax update ----------
__device__ __forceinline__ void online_update(float logit, const float4& xlv, float& m,
                                              float& den, float4& acc) {
    float mn = fmaxf(m, logit);
    float s = __expf(m - mn);
    float w = __expf(logit - mn);
    den = den * s + w;
    acc.x = fmaf(w, xlv.x, acc.x * s);
    acc.y = fmaf(w, xlv.y, acc.y * s);
    acc.z = fmaf(w, xlv.z, acc.z * s);
    acc.w = fmaf(w, xlv.w, acc.w * s);
    m = mn;
}

template <bool L0>
__device__ __forceinline__ float edge_logit(const float4& xlv, const float4& xrv,
                                            const float4* Wreg, float a, const float4& av) {
    float m0 = xlv.x + xrv.x, m1 = xlv.y + xrv.y, m2 = xlv.z + xrv.z, m3 = xlv.w + xrv.w;
    if (L0) {
#pragma unroll
        for (int j = 0; j < 11; ++j) {
            float aj = __shfl(a, j);
            m0 = fmaf(aj, Wreg[j].x, m0);
            m1 = fmaf(aj, Wreg[j].y, m1);
            m2 = fmaf(aj, Wreg[j].z, m2);
            m3 = fmaf(aj, Wreg[j].w, m3);
        }
    }
    m0 = m0 > 0.f ? m0 : SLOPE * m0;
    m1 = m1 > 0.f ? m1 : SLOPE * m1;
    m2 = m2 > 0.f ? m2 : SLOPE * m2;
    m3 = m3 > 0.f ? m3 : SLOPE * m3;
    float p = m0 * av.x + m1 * av.y + m2 * av.z + m3 * av.w;
    p += __shfl_xor(p, 1);
    p += __shfl_xor(p, 2);
    p += __shfl_xor(p, 4);
    return p;
}

// ---------- fused per-node gather: logits + online softmax + accumulate ----------
template <bool L0>
__global__ __launch_bounds__(256) void node_gather_kernel(
    const int* __restrict__ offs, const int* __restrict__ esrc, const int* __restrict__ eidx,
    const float* __restrict__ ea, const float* __restrict__ mean_ea,
    const float* __restrict__ We, const float* __restrict__ att, const float* __restrict__ xl,
    const float* __restrict__ xr, const float* __restrict__ bias, float* __restrict__ out,
    int Nn, int E) {
    int wid = threadIdx.x >> 6;
    int lane = threadIdx.x & 63;
    int node = blockIdx.x * 4 + wid;
    if (node >= Nn) return;
    int c4 = lane * 4;

    float4 Wreg[11];
    if (L0) {
#pragma unroll
        for (int j = 0; j < 11; ++j) Wreg[j] = *(const float4*)(We + j * N_HC + c4);
    }
    const float4 xrv = *(const float4*)(xr + (size_t)node * N_HC + c4);
    const float4 av = *(const float4*)(att + c4);

    int beg = offs[node], end = offs[node + 1];

    float mA = -INFINITY, dA = 0.f;
    float mB = -INFINITY, dB = 0.f;
    float4 aA = {0.f, 0.f, 0.f, 0.f}, aB = {0.f, 0.f, 0.f, 0.f};

    int p = beg;
    for (; p + 1 < end; p += 2) {
        int s0 = esrc[p], s1 = esrc[p + 1];
        const float4 x0 = *(const float4*)(xl + (size_t)s0 * N_HC + c4);
        const float4 x1 = *(const float4*)(xl + (size_t)s1 * N_HC + c4);
        float a0 = 0.f, a1 = 0.f;
        if (L0) {
            int e0 = eidx[p], e1 = eidx[p + 1];
            if (lane < 11) {
                a0 = (e0 < E) ? ea[(size_t)e0 * 11 + lane] : mean_ea[lane];
                a1 = (e1 < E) ? ea[(size_t)e1 * 11 + lane] : mean_ea[lane];
            }
            float q00 = __shfl(a0, 0), q09 = __shfl(a0, 9);
            float q10 = __shfl(a1, 0), q19 = __shfl(a1, 9);
            if (e0 < E && lane == 1 && q09 == 1.0f) a0 = (a0 - q00) * 0.01f;
            if (e1 < E && lane == 1 && q19 == 1.0f) a1 = (a1 - q10) * 0.01f;
        }
        float p0 = edge_logit<L0>(x0, xrv, Wreg, a0, av);
        float p1 = edge_logit<L0>(x1, xrv, Wreg, a1, av);
        online_update(p0, x0, mA, dA, aA);
        online_update(p1, x1, mB, dB, aB);
    }
    if (p < end) {
        int s0 = esrc[p];
        const float4 x0 = *(const float4*)(xl + (size_t)s0 * N_HC + c4);
        float a0 = 0.f;
        if (L0) {
            int e0 = eidx[p];
            if (lane < 11) a0 = (e0 < E) ? ea[(size_t)e0 * 11 + lane] : mean_ea[lane];
            float q00 = __shfl(a0, 0), q09 = __shfl(a0, 9);
            if (e0 < E && lane == 1 && q09 == 1.0f) a0 = (a0 - q00) * 0.01f;
        }
        float p0 = edge_logit<L0>(x0, xrv, Wreg, a0, av);
        online_update(p0, x0, mA, dA, aA);
    }

    // merge B into A
    float mm = fmaxf(mA, mB);
    float sA = __expf(mA - mm), sB = __expf(mB - mm);
    float den = dA * sA + dB * sB;
    float4 acc;
    acc.x = aA.x * sA + aB.x * sB;
    acc.y = aA.y * sA + aB.y * sB;
    acc.z = aA.z * sA + aB.z * sB;
    acc.w = aA.w * sA + aB.w * sB;

    const float4 bv = *(const float4*)(bias + c4);
    float4 r;
    r.x = acc.x / den + bv.x;
    r.y = acc.y / den + bv.y;
    r.z = acc.z / den + bv.z;
    r.w = acc.w / den + bv.w;
    if (L0) {
        r.x = r.x > 0.f ? r.x : (__expf(r.x) - 1.f);
        r.y = r.y > 0.f ? r.y : (__expf(r.y) - 1.f);
        r.z = r.z > 0.f ? r.z : (__expf(r.z) - 1.f);
        r.w = r.w > 0.f ? r.w : (__expf(r.w) - 1.f);
    }
    *(float4*)(out + (size_t)node * N_HC + c4) = r;
}

extern "C" void kernel_launch(void* const* d_in, const int* in_sizes, int n_in, void* d_out,
                              int out_size, void* d_ws, size_t ws_size, hipStream_t stream) {
    const float* x = (const float*)d_in[0];
    const int* ei = (const int*)d_in[1];
    const float* ea = (const float*)d_in[2];
    const float* Wl0 = (const float*)d_in[3];
    const float* bl0 = (const float*)d_in[4];
    const float* Wr0 = (const float*)d_in[5];
    const float* br0 = (const float*)d_in[6];
    const float* We0 = (const float*)d_in[7];
    const float* att0 = (const float*)d_in[8];
    const float* bias0 = (const float*)d_in[9];
    const float* Wl1 = (const float*)d_in[10];
    const float* bl1 = (const float*)d_in[11];
    const float* Wr1 = (const float*)d_in[12];
    const float* br1 = (const float*)d_in[13];
    const float* att1 = (const float*)d_in[14];
    const float* bias1 = (const float*)d_in[15];
    float* out = (float*)d_out;

    const int Nn = in_sizes[0] / 6;
    const int E = in_sizes[1] / 2;
    const int Etot = E + Nn;

    auto align16 = [](size_t v) { return (v + 15) & ~(size_t)15; };
    float* ws = (float*)d_ws;
    size_t o = 0;
    float* xp = ws + o;    o = align16(o + (size_t)Nn * 6);
    float* xl = ws + o;    o = align16(o + (size_t)Nn * N_HC);
    float* xr = ws + o;    o = align16(o + (size_t)Nn * N_HC);
    float* h = ws + o;     o = align16(o + (size_t)Nn * N_HC);
    float* easum = ws + o; o = align16(o + 16);
    float* mean = ws + o;  o = align16(o + 16);
    int* deg = (int*)(ws + o);    o = align16(o + (size_t)Nn);
    int* offs = (int*)(ws + o);   o = align16(o + (size_t)Nn + 1);
    int* cursor = (int*)(ws + o); o = align16(o + (size_t)Nn);
    int* esrc = (int*)(ws + o);   o = align16(o + (size_t)Etot);
    int* eidx = (int*)(ws + o);   o = align16(o + (size_t)Etot);

    hipMemsetAsync(easum, 0, 16 * sizeof(float), stream);
    hipMemsetAsync(deg, 0, (size_t)Nn * sizeof(int), stream);

    // preprocessing
    pre_x_kernel<<<(Nn + 255) / 256, 256, 0, stream>>>(x, xp, Nn);
    ea_colsum_kernel<<<256, 256, 0, stream>>>(ea, easum, E);
    mean_div_kernel<<<1, 32, 0, stream>>>(easum, mean, E);

    // CSR build (shared across both layers)
    deg_hist_kernel<<<(Etot + 255) / 256, 256, 0, stream>>>(ei, deg, E, Etot);
    scan_kernel<<<1, 1024, 0, stream>>>(deg, offs, cursor, Nn);
    scatter_kernel<<<(Etot + 255) / 256, 256, 0, stream>>>(ei, cursor, esrc, eidx, E, Etot);

    const int gblocks = (Nn + 3) / 4;

    // layer 0
    node_mm_kernel<6, 8><<<(Nn + 7) / 8, 256, 0, stream>>>(xp, Wl0, bl0, Wr0, br0, xl, xr, Nn);
    node_gather_kernel<true><<<gblocks, 256, 0, stream>>>(offs, esrc, eidx, ea, mean, We0, att0,
                                                          xl, xr, bias0, h, Nn, E);

    // layer 1
    dim3 ggrid((Nn + 127) / 128, 4);
    gemm256_kernel<<<ggrid, 256, 0, stream>>>(h, Wl1, bl1, Wr1, br1, xl, xr, Nn);
    node_gather_kernel<false><<<gblocks, 256, 0, stream>>>(offs, esrc, eidx, nullptr, nullptr,
                                                           nullptr, att1, xl, xr, bias1, out, Nn,
                                                           E);
}